// Round 3
// baseline (390.243 us; speedup 1.0000x reference)
//
#include <hip/hip_runtime.h>

#define SEQ 65536
#define DIM 1024

// ws layout (floats):
// [0,1024)     w    = q @ W1
// [1024,2048)  w2q  = q @ W2
// [2048]       c0
// [4096, 4096 + nb*1024) : per-block partials of out

__global__ void k_init(float* __restrict__ ws, float* __restrict__ out) {
    int t = blockIdx.x * 256 + threadIdx.x;   // grid 16 -> 4096 threads
    if (t < 4096) ws[t] = 0.0f;
    if (t < DIM)  out[t] = 0.0f;
}

// w[col]   = sum_d q[d] * W1[d*DIM + col]   (blockIdx.z == 0)
// w2q[col] = sum_d q[d] * W2[d*DIM + col]   (blockIdx.z == 1)
__global__ void k_qmat(const float* __restrict__ W1,
                       const float* __restrict__ W2,
                       const float* __restrict__ q,
                       float* __restrict__ ws) {
    const float* M = (blockIdx.z == 0) ? W1 : W2;
    float* dst = ws + blockIdx.z * DIM;
    int col = blockIdx.x * 256 + threadIdx.x;
    int d0  = blockIdx.y * 128;
    float s = 0.0f;
#pragma unroll 8
    for (int d = 0; d < 128; ++d) {
        s += q[d0 + d] * M[(size_t)(d0 + d) * DIM + col];
    }
    atomicAdd(&dst[col], s);
}

// c0 = dot(w2q, v[SEQ-1]) + b * sum(q)
__global__ void k_c0(const float* __restrict__ v,
                     const float* __restrict__ q,
                     const float* __restrict__ b,
                     float* __restrict__ ws) {
    __shared__ float red[1024];
    int t = threadIdx.x;                       // 1024 threads
    const float* vn = v + (size_t)(SEQ - 1) * DIM;
    float val = ws[1024 + t] * vn[t] + b[0] * q[t];
    red[t] = val;
    __syncthreads();
    for (int off = 512; off > 0; off >>= 1) {
        if (t < off) red[t] += red[t + off];
        __syncthreads();
    }
    if (t == 0) ws[2048] = red[0];
}

// Fused: per row s, score = w . v[s] + c0; partial_out += score * v[s]
__launch_bounds__(256, 4)
__global__ void k_main(const float* __restrict__ v,
                       const float* __restrict__ ws,
                       float* __restrict__ part, int nb) {
    __shared__ float sacc[DIM];
    const int tid  = threadIdx.x;
    const int lane = tid & 63;
    const int wid  = tid >> 6;

    const float c0 = ws[2048];
    const float4* wq = (const float4*)(ws + lane * 16);
    float4 w0 = wq[0], w1 = wq[1], w2 = wq[2], w3 = wq[3];

    float4 a0 = {0,0,0,0}, a1 = {0,0,0,0}, a2 = {0,0,0,0}, a3 = {0,0,0,0};

    const int gw = blockIdx.x * 4 + wid;      // global wave id
    const int nw = nb * 4;                     // total waves

    for (int s = gw; s < SEQ; s += nw) {
        const float4* row = (const float4*)(v + (size_t)s * DIM + lane * 16);
        float4 ra = row[0], rb = row[1], rc = row[2], rd = row[3];

        float p = ra.x * w0.x + ra.y * w0.y + ra.z * w0.z + ra.w * w0.w
                + rb.x * w1.x + rb.y * w1.y + rb.z * w1.z + rb.w * w1.w
                + rc.x * w2.x + rc.y * w2.y + rc.z * w2.z + rc.w * w2.w
                + rd.x * w3.x + rd.y * w3.y + rd.z * w3.z + rd.w * w3.w;
#pragma unroll
        for (int off = 1; off < 64; off <<= 1)
            p += __shfl_xor(p, off, 64);
        float score = p + c0;

        a0.x += score * ra.x; a0.y += score * ra.y; a0.z += score * ra.z; a0.w += score * ra.w;
        a1.x += score * rb.x; a1.y += score * rb.y; a1.z += score * rb.z; a1.w += score * rb.w;
        a2.x += score * rc.x; a2.y += score * rc.y; a2.z += score * rc.z; a2.w += score * rc.w;
        a3.x += score * rd.x; a3.y += score * rd.y; a3.z += score * rd.z; a3.w += score * rd.w;
    }

    for (int i = tid; i < DIM; i += 256) sacc[i] = 0.0f;
    __syncthreads();

    for (int wv = 0; wv < 4; ++wv) {
        if (wid == wv) {
            float* s0 = sacc + lane * 16;
            s0[0]  += a0.x; s0[1]  += a0.y; s0[2]  += a0.z; s0[3]  += a0.w;
            s0[4]  += a1.x; s0[5]  += a1.y; s0[6]  += a1.z; s0[7]  += a1.w;
            s0[8]  += a2.x; s0[9]  += a2.y; s0[10] += a2.z; s0[11] += a2.w;
            s0[12] += a3.x; s0[13] += a3.y; s0[14] += a3.z; s0[15] += a3.w;
        }
        __syncthreads();
    }

    float* dst = part + (size_t)blockIdx.x * DIM;
    for (int i = tid; i < DIM; i += 256) dst[i] = sacc[i];
}

__global__ void k_reduce(const float* __restrict__ part,
                         float* __restrict__ out, int nb) {
    int col = blockIdx.x * 256 + threadIdx.x;
    int chunk = (nb + 31) / 32;
    int b0 = blockIdx.y * chunk;
    int b1 = min(nb, b0 + chunk);
    float s = 0.0f;
    for (int bdx = b0; bdx < b1; ++bdx)
        s += part[(size_t)bdx * DIM + col];
    atomicAdd(&out[col], s);
}

extern "C" void kernel_launch(void* const* d_in, const int* in_sizes, int n_in,
                              void* d_out, int out_size, void* d_ws, size_t ws_size,
                              hipStream_t stream) {
    const float* v  = (const float*)d_in[0];
    const float* W1 = (const float*)d_in[1];
    const float* W2 = (const float*)d_in[2];
    const float* q  = (const float*)d_in[3];
    const float* b  = (const float*)d_in[4];
    float* out = (float*)d_out;
    float* ws  = (float*)d_ws;

    size_t avail = ws_size / sizeof(float);
    int nb = 1024;
    if ((size_t)(4096 + (size_t)nb * DIM) > avail)
        nb = (int)((avail - 4096) / DIM);
    if (nb < 1) nb = 1;
    float* part = ws + 4096;

    k_init<<<dim3(16), dim3(256), 0, stream>>>(ws, out);
    k_qmat<<<dim3(4, 8, 2), dim3(256), 0, stream>>>(W1, W2, q, ws);
    k_c0<<<dim3(1), dim3(1024), 0, stream>>>(v, q, b, ws);
    k_main<<<dim3(nb), dim3(256), 0, stream>>>(v, ws, part, nb);
    k_reduce<<<dim3(4, 32), dim3(256), 0, stream>>>(part, out, nb);
}

// Round 4
// 380.780 us; speedup vs baseline: 1.0249x; 1.0249x over previous
//
#include <hip/hip_runtime.h>

#define SEQ 65536
#define DIM 1024
#define NB  1024          // k_main blocks
#define NW  (NB * 4)      // total waves in k_main

typedef float f32x4 __attribute__((ext_vector_type(4)));

// ws layout (floats):
// [0,1024)          w   = q @ W1
// [2048]            c0  = (q@W2) . v[SEQ-1] + b * sum(q)
// [3072, 3072+32*1024) : qmat partials (16 for W1, 16 for W2)

// Partial products: block (x,y,z) sums 64 d's for 256 cols of W{z+1}.
// Plain stores (no init / no atomics needed).
__global__ void k_qmat(const float* __restrict__ W1,
                       const float* __restrict__ W2,
                       const float* __restrict__ q,
                       float* __restrict__ ws) {
    const float* M = blockIdx.z ? W2 : W1;
    int col = blockIdx.x * 256 + threadIdx.x;   // 4 x-blocks
    int d0  = blockIdx.y * 64;                  // 16 y-blocks
    float s = 0.0f;
#pragma unroll 8
    for (int d = 0; d < 64; ++d)
        s += q[d0 + d] * M[(size_t)(d0 + d) * DIM + col];
    ws[3072 + (blockIdx.z * 16 + blockIdx.y) * DIM + col] = s;
}

// One block, 1024 threads: reduce partials -> w (ws[0..1024)), compute c0,
// zero out[].
__global__ void k_prep(const float* __restrict__ v,
                       const float* __restrict__ q,
                       const float* __restrict__ b,
                       float* __restrict__ ws,
                       float* __restrict__ out) {
    __shared__ float red[1024];
    int t = threadIdx.x;
    const float* p = ws + 3072;
    float w = 0.0f, w2 = 0.0f;
#pragma unroll
    for (int y = 0; y < 16; ++y) {
        w  += p[y * DIM + t];
        w2 += p[(16 + y) * DIM + t];
    }
    ws[t] = w;
    const float* vn = v + (size_t)(SEQ - 1) * DIM;
    red[t] = w2 * vn[t] + b[0] * q[t];
    __syncthreads();
    for (int off = 512; off > 0; off >>= 1) {
        if (t < off) red[t] += red[t + off];
        __syncthreads();
    }
    if (t == 0) ws[2048] = red[0];
    out[t] = 0.0f;
}

// Fused pass over v: score[s] = w.v[s] + c0 ; out += score[s] * v[s].
// Wave-per-row, 2 rows per iteration for ILP; atomic accumulate into out.
__launch_bounds__(256, 4)
__global__ void k_main(const float* __restrict__ v,
                       const float* __restrict__ ws,
                       float* __restrict__ out) {
    __shared__ float sacc[DIM];
    const int tid  = threadIdx.x;
    const int lane = tid & 63;
    const int wid  = tid >> 6;

    const float c0 = ws[2048];
    const f32x4* wq = (const f32x4*)(ws + lane * 16);
    f32x4 w0 = wq[0], w1 = wq[1], w2 = wq[2], w3 = wq[3];

    f32x4 a0 = 0.0f, a1 = 0.0f, a2 = 0.0f, a3 = 0.0f;

    const int gw = blockIdx.x * 4 + wid;

    for (int s = gw; s < SEQ; s += 2 * NW) {
        const int sB = s + NW;
        const bool hb = sB < SEQ;

        const f32x4* rA = (const f32x4*)(v + (size_t)s * DIM + lane * 16);
        f32x4 ra0 = __builtin_nontemporal_load(&rA[0]);
        f32x4 ra1 = __builtin_nontemporal_load(&rA[1]);
        f32x4 ra2 = __builtin_nontemporal_load(&rA[2]);
        f32x4 ra3 = __builtin_nontemporal_load(&rA[3]);

        const f32x4* rB = (const f32x4*)(v + (size_t)(hb ? sB : s) * DIM + lane * 16);
        f32x4 rb0 = __builtin_nontemporal_load(&rB[0]);
        f32x4 rb1 = __builtin_nontemporal_load(&rB[1]);
        f32x4 rb2 = __builtin_nontemporal_load(&rB[2]);
        f32x4 rb3 = __builtin_nontemporal_load(&rB[3]);

        float pA = ra0.x*w0.x + ra0.y*w0.y + ra0.z*w0.z + ra0.w*w0.w
                 + ra1.x*w1.x + ra1.y*w1.y + ra1.z*w1.z + ra1.w*w1.w
                 + ra2.x*w2.x + ra2.y*w2.y + ra2.z*w2.z + ra2.w*w2.w
                 + ra3.x*w3.x + ra3.y*w3.y + ra3.z*w3.z + ra3.w*w3.w;
        float pB = rb0.x*w0.x + rb0.y*w0.y + rb0.z*w0.z + rb0.w*w0.w
                 + rb1.x*w1.x + rb1.y*w1.y + rb1.z*w1.z + rb1.w*w1.w
                 + rb2.x*w2.x + rb2.y*w2.y + rb2.z*w2.z + rb2.w*w2.w
                 + rb3.x*w3.x + rb3.y*w3.y + rb3.z*w3.z + rb3.w*w3.w;

#pragma unroll
        for (int off = 1; off < 64; off <<= 1) {
            pA += __shfl_xor(pA, off, 64);
            pB += __shfl_xor(pB, off, 64);
        }
        float scoreA = pA + c0;
        float scoreB = pB + c0;

        a0 += scoreA * ra0; a1 += scoreA * ra1; a2 += scoreA * ra2; a3 += scoreA * ra3;
        if (hb) {
            a0 += scoreB * rb0; a1 += scoreB * rb1; a2 += scoreB * rb2; a3 += scoreB * rb3;
        }
    }

    for (int i = tid; i < DIM; i += 256) sacc[i] = 0.0f;
    __syncthreads();

    for (int wv = 0; wv < 4; ++wv) {
        if (wid == wv) {
            float* s0 = sacc + lane * 16;
            s0[0]  += a0.x; s0[1]  += a0.y; s0[2]  += a0.z; s0[3]  += a0.w;
            s0[4]  += a1.x; s0[5]  += a1.y; s0[6]  += a1.z; s0[7]  += a1.w;
            s0[8]  += a2.x; s0[9]  += a2.y; s0[10] += a2.z; s0[11] += a2.w;
            s0[12] += a3.x; s0[13] += a3.y; s0[14] += a3.z; s0[15] += a3.w;
        }
        __syncthreads();
    }

    for (int i = tid; i < DIM; i += 256)
        atomicAdd(&out[i], sacc[i]);
}

extern "C" void kernel_launch(void* const* d_in, const int* in_sizes, int n_in,
                              void* d_out, int out_size, void* d_ws, size_t ws_size,
                              hipStream_t stream) {
    const float* v  = (const float*)d_in[0];
    const float* W1 = (const float*)d_in[1];
    const float* W2 = (const float*)d_in[2];
    const float* q  = (const float*)d_in[3];
    const float* b  = (const float*)d_in[4];
    float* out = (float*)d_out;
    float* ws  = (float*)d_ws;

    k_qmat<<<dim3(4, 16, 2), dim3(256), 0, stream>>>(W1, W2, q, ws);
    k_prep<<<dim3(1), dim3(1024), 0, stream>>>(v, q, b, ws, out);
    k_main<<<dim3(NB), dim3(256), 0, stream>>>(v, ws, out);
}